// Round 2
// baseline (3315.629 us; speedup 1.0000x reference)
//
#include <hip/hip_runtime.h>

#define DI __device__ __forceinline__

constexpr int Bb = 2, Ss = 4096, Hm = 2048, NHh = 16, HDd = 128;
constexpr int ROWS = Bb * Ss;   // 8192
constexpr int QKVN = 3 * Hm;    // 6144

typedef __bf16 bf16x8 __attribute__((ext_vector_type(8)));
typedef float f32x4 __attribute__((ext_vector_type(4)));

DI unsigned short f2bf(float f) {
  unsigned int u = __float_as_uint(f);
  u = u + 0x7FFFu + ((u >> 16) & 1u);   // round-to-nearest-even
  return (unsigned short)(u >> 16);
}
DI float bf2f(unsigned int u) { return __uint_as_float(u << 16); }
DI void ld_bf8(const unsigned short* p, float* f) {
  uint4 u = *(const uint4*)p;
  f[0] = bf2f(u.x & 0xffffu); f[1] = bf2f(u.x >> 16);
  f[2] = bf2f(u.y & 0xffffu); f[3] = bf2f(u.y >> 16);
  f[4] = bf2f(u.z & 0xffffu); f[5] = bf2f(u.z >> 16);
  f[6] = bf2f(u.w & 0xffffu); f[7] = bf2f(u.w >> 16);
}

// ---------------- cast x -> bf16 ----------------
__global__ void cast_x_k(const float* __restrict__ x, unsigned short* __restrict__ xb) {
  int i = blockIdx.x * 256 + threadIdx.x;
  float4 f = ((const float4*)x)[i];
  ushort4 u;
  u.x = f2bf(f.x); u.y = f2bf(f.y); u.z = f2bf(f.z); u.w = f2bf(f.w);
  ((ushort4*)xb)[i] = u;
}

// ---------------- cast weights -> bf16 (Wq|Wk|Wv concat, Wo) ----------------
__global__ void cast_w_k(const float* __restrict__ Wq, const float* __restrict__ Wk,
                         const float* __restrict__ Wv, const float* __restrict__ Wo,
                         unsigned short* __restrict__ wqkv, unsigned short* __restrict__ wo) {
  const int W1 = Hm * Hm;  // 4194304
  int idx = blockIdx.x * 256 + threadIdx.x;
  for (int r = 0; r < 4; r++) {
    int i = idx + r * W1;
    if (i < W1)            wqkv[i] = f2bf(Wq[i]);
    else if (i < 2 * W1)   wqkv[i] = f2bf(Wk[i - W1]);
    else if (i < 3 * W1)   wqkv[i] = f2bf(Wv[i - 2 * W1]);
    else                   wo[i - 3 * W1] = f2bf(Wo[i - 3 * W1]);
  }
}

// ---------------- bf16 NT GEMM: C[M][N] = A[M][Kd] * B[N][Kd]^T ----------------
// 128x128 tile, BK=32, 256 threads = 4 waves (2x2), each wave 64x64 via 4x4 mfma_16x16x32
template <bool BF16_OUT>
__global__ __launch_bounds__(256) void gemm_bt(const unsigned short* __restrict__ A,
                                               const unsigned short* __restrict__ Bm,
                                               void* __restrict__ Cout,
                                               int M, int N, int Kd) {
  __shared__ __align__(16) unsigned short As[128 * 32];
  __shared__ __align__(16) unsigned short Bs[128 * 32];
  int tid = threadIdx.x;
  int bm = blockIdx.y * 128, bn = blockIdx.x * 128;
  int wave = tid >> 6, lane = tid & 63;
  int wm = (wave >> 1) * 64, wn = (wave & 1) * 64;
  int lm = lane & 15, lq = lane >> 4;
  f32x4 acc[4][4] = {};
  int lr = tid >> 2;          // 0..63
  int lc = (tid & 3) * 8;     // 0,8,16,24

  for (int k0 = 0; k0 < Kd; k0 += 32) {
    __syncthreads();
    *(uint4*)&As[lr * 32 + lc]        = *(const uint4*)&A[(size_t)(bm + lr) * Kd + k0 + lc];
    *(uint4*)&As[(lr + 64) * 32 + lc] = *(const uint4*)&A[(size_t)(bm + lr + 64) * Kd + k0 + lc];
    *(uint4*)&Bs[lr * 32 + lc]        = *(const uint4*)&Bm[(size_t)(bn + lr) * Kd + k0 + lc];
    *(uint4*)&Bs[(lr + 64) * 32 + lc] = *(const uint4*)&Bm[(size_t)(bn + lr + 64) * Kd + k0 + lc];
    __syncthreads();
    bf16x8 af[4], bfr[4];
#pragma unroll
    for (int i = 0; i < 4; i++) af[i]  = *(const bf16x8*)&As[(wm + i * 16 + lm) * 32 + lq * 8];
#pragma unroll
    for (int j = 0; j < 4; j++) bfr[j] = *(const bf16x8*)&Bs[(wn + j * 16 + lm) * 32 + lq * 8];
#pragma unroll
    for (int i = 0; i < 4; i++)
#pragma unroll
      for (int j = 0; j < 4; j++)
        acc[i][j] = __builtin_amdgcn_mfma_f32_16x16x32_bf16(af[i], bfr[j], acc[i][j], 0, 0, 0);
  }
#pragma unroll
  for (int i = 0; i < 4; i++)
#pragma unroll
    for (int j = 0; j < 4; j++) {
      int row = bm + wm + i * 16 + lq * 4;
      int col = bn + wn + j * 16 + lm;
#pragma unroll
      for (int r = 0; r < 4; r++) {
        if (BF16_OUT)
          ((unsigned short*)Cout)[(size_t)(row + r) * N + col] = f2bf(acc[i][j][r]);
        else
          ((float*)Cout)[(size_t)(row + r) * N + col] = acc[i][j][r];
      }
    }
}

// ---------------- causal conv K=4 + silu + (l2norm for q/k), bf16 in/out ----------------
// grid: (Hm/256 chblk, Ss/32 strip, B*3), 256 threads (1 channel each, 32 s-positions)
__global__ __launch_bounds__(256) void conv_k(const unsigned short* __restrict__ qkvh,
                                              const float* __restrict__ cwq,
                                              const float* __restrict__ cwk,
                                              const float* __restrict__ cwv,
                                              unsigned short* __restrict__ qb,
                                              unsigned short* __restrict__ kb,
                                              unsigned short* __restrict__ vb) {
  __shared__ __align__(16) float sm[32 * 256];
  __shared__ float fac[64];
  int tid = threadIdx.x;
  int cblk = blockIdx.x * 256;
  int s0 = blockIdx.y * 32;
  int z = blockIdx.z;
  int sel = z >> 1, b = z & 1;
  const float* cw = sel == 0 ? cwq : (sel == 1 ? cwk : cwv);
  int c = cblk + tid;
  float4 w = ((const float4*)cw)[c];  // cw[c][0..3]
  const unsigned short* in = qkvh + (size_t)b * Ss * QKVN + sel * Hm + c;
  float x0 = (s0 >= 3) ? bf2f(in[(size_t)(s0 - 3) * QKVN]) : 0.f;
  float x1 = (s0 >= 2) ? bf2f(in[(size_t)(s0 - 2) * QKVN]) : 0.f;
  float x2 = (s0 >= 1) ? bf2f(in[(size_t)(s0 - 1) * QKVN]) : 0.f;
  for (int si = 0; si < 32; si++) {
    float x3 = bf2f(in[(size_t)(s0 + si) * QKVN]);
    float a = w.x * x0 + w.y * x1 + w.z * x2 + w.w * x3;
    sm[si * 256 + tid] = a / (1.f + __expf(-a));  // silu
    x0 = x1; x1 = x2; x2 = x3;
  }
  __syncthreads();
  if (sel < 2) {
    int si = tid >> 3, p = tid & 7;   // p*32 = channel offset; p 0-3 head A, 4-7 head B
    const float* row = &sm[si * 256 + p * 32];
    float ss = 0.f;
#pragma unroll
    for (int j = 0; j < 32; j += 4) {
      float4 v4 = *(const float4*)(row + j);
      ss += v4.x * v4.x + v4.y * v4.y + v4.z * v4.z + v4.w * v4.w;
    }
    ss += __shfl_xor(ss, 1);
    ss += __shfl_xor(ss, 2);
    float f = rsqrtf(ss + 1e-6f);
    if (sel == 0) f *= 0.08838834764831845f;  // * hd^-0.5 for q
    if ((p & 3) == 0) fac[si * 2 + (p >> 2)] = f;
  }
  __syncthreads();
  unsigned short* outp = sel == 0 ? qb : (sel == 1 ? kb : vb);
  int hl = tid >> 7;
  for (int si = 0; si < 32; si++) {
    float val = sm[si * 256 + tid];
    if (sel < 2) val *= fac[si * 2 + hl];
    outp[(size_t)(b * Ss + s0 + si) * Hm + cblk + tid] = f2bf(val);
  }
}

// ---------------- beta = sigmoid(x @ Wb^T), fp32 ----------------
__global__ __launch_bounds__(256) void beta_k(const float* __restrict__ x,
                                              const float* __restrict__ Wbm,
                                              float* __restrict__ beta) {
  int wid = threadIdx.x >> 6, lane = threadIdx.x & 63;
  int row = blockIdx.x * 4 + wid;
  int h = lane & 15, part = lane >> 4;
  const float* xr = x + (size_t)row * Hm + part * 512;
  const float* wr = Wbm + (size_t)h * Hm + part * 512;
  float acc = 0.f;
  for (int j = 0; j < 512; j += 4) {
    float4 xv = *(const float4*)(xr + j);
    float4 wv = *(const float4*)(wr + j);
    acc += xv.x * wv.x + xv.y * wv.y + xv.z * wv.z + xv.w * wv.w;
  }
  acc += __shfl_xor(acc, 16);
  acc += __shfl_xor(acc, 32);
  if (part == 0) beta[(size_t)row * NHh + h] = 1.f / (1.f + __expf(-acc));
}

// ---------------- delta-rule recurrence, v-column-parallel, bf16 in/out, fp32 state ----------------
// grid 256 = 32 (b,h) x 8 v-blocks of 16 cols. 256 thr: dg=tid&15 (8 d each), vl=tid>>4
__global__ __launch_bounds__(256) void rec_k(const unsigned short* __restrict__ q,
                                             const unsigned short* __restrict__ k,
                                             const unsigned short* __restrict__ v,
                                             const float* __restrict__ beta,
                                             unsigned short* __restrict__ o) {
  int tid = threadIdx.x;
  int dg = tid & 15, vl = tid >> 4;
  int bh = blockIdx.x >> 3, vblk = blockIdx.x & 7;
  int b = bh >> 4, h = bh & 15;
  int vcol = vblk * 16 + vl, d0 = dg * 8;
  size_t base = (size_t)b * Ss * Hm + h * HDd;
  const unsigned short* kp = k + base + d0;
  const unsigned short* qp = q + base + d0;
  const unsigned short* vp = v + base + vcol;
  const float* bp = beta + (size_t)b * Ss * NHh + h;
  unsigned short* op = o + base + vcol;
  float st[8];
#pragma unroll
  for (int i = 0; i < 8; i++) st[i] = 0.f;
  float ka[8], qa[8];
  ld_bf8(kp, ka);
  ld_bf8(qp, qa);
  float vt = bf2f(*vp), bt = *bp;
  for (int t = 0; t < Ss; t++) {
    int tn = (t + 1 < Ss) ? t + 1 : t;
    size_t ro = (size_t)tn * Hm;
    uint4 nk = *(const uint4*)(kp + ro);
    uint4 nq = *(const uint4*)(qp + ro);
    float nvt = bf2f(vp[ro]);
    float nbt = bp[(size_t)tn * NHh];
    float p0 = ka[0] * st[0] + ka[1] * st[1] + ka[2] * st[2] + ka[3] * st[3];
    float p1 = ka[4] * st[4] + ka[5] * st[5] + ka[6] * st[6] + ka[7] * st[7];
    float p = p0 + p1;
    p += __shfl_xor(p, 1); p += __shfl_xor(p, 2); p += __shfl_xor(p, 4); p += __shfl_xor(p, 8);
    float delta = bt * (vt - p);
#pragma unroll
    for (int i = 0; i < 8; i++) st[i] += ka[i] * delta;
    float o0 = qa[0] * st[0] + qa[1] * st[1] + qa[2] * st[2] + qa[3] * st[3];
    float o1 = qa[4] * st[4] + qa[5] * st[5] + qa[6] * st[6] + qa[7] * st[7];
    float ov = o0 + o1;
    ov += __shfl_xor(ov, 1); ov += __shfl_xor(ov, 2); ov += __shfl_xor(ov, 4); ov += __shfl_xor(ov, 8);
    if (dg == 0) op[(size_t)t * Hm] = f2bf(ov);
    // unpack prefetched next-row fragments
    ka[0] = bf2f(nk.x & 0xffffu); ka[1] = bf2f(nk.x >> 16);
    ka[2] = bf2f(nk.y & 0xffffu); ka[3] = bf2f(nk.y >> 16);
    ka[4] = bf2f(nk.z & 0xffffu); ka[5] = bf2f(nk.z >> 16);
    ka[6] = bf2f(nk.w & 0xffffu); ka[7] = bf2f(nk.w >> 16);
    qa[0] = bf2f(nq.x & 0xffffu); qa[1] = bf2f(nq.x >> 16);
    qa[2] = bf2f(nq.y & 0xffffu); qa[3] = bf2f(nq.y >> 16);
    qa[4] = bf2f(nq.z & 0xffffu); qa[5] = bf2f(nq.z >> 16);
    qa[6] = bf2f(nq.w & 0xffffu); qa[7] = bf2f(nq.w >> 16);
    vt = nvt; bt = nbt;
  }
}

// ---------------- RMSNorm over head_dim + bf16 in/out ----------------
__global__ __launch_bounds__(256) void rmsn_k(const unsigned short* __restrict__ o,
                                              const float* __restrict__ rw,
                                              unsigned short* __restrict__ ob) {
  int tid = threadIdx.x;
  size_t rowoff = (size_t)blockIdx.x * Hm + tid * 8;
  float f[8];
  ld_bf8(o + rowoff, f);
  float ss = f[0]*f[0] + f[1]*f[1] + f[2]*f[2] + f[3]*f[3] +
             f[4]*f[4] + f[5]*f[5] + f[6]*f[6] + f[7]*f[7];
  ss += __shfl_xor(ss, 1); ss += __shfl_xor(ss, 2); ss += __shfl_xor(ss, 4); ss += __shfl_xor(ss, 8);
  float sc = rsqrtf(ss * (1.f / 128.f) + 1e-5f);
  int d = (tid & 15) * 8;
  float4 wa = *(const float4*)(rw + d);
  float4 wb = *(const float4*)(rw + d + 4);
  ushort4 u0, u1;
  u0.x = f2bf(f[0] * sc * wa.x); u0.y = f2bf(f[1] * sc * wa.y);
  u0.z = f2bf(f[2] * sc * wa.z); u0.w = f2bf(f[3] * sc * wa.w);
  u1.x = f2bf(f[4] * sc * wb.x); u1.y = f2bf(f[5] * sc * wb.y);
  u1.z = f2bf(f[6] * sc * wb.z); u1.w = f2bf(f[7] * sc * wb.w);
  ((ushort4*)ob)[rowoff / 4] = u0;
  ((ushort4*)ob)[rowoff / 4 + 1] = u1;
}

extern "C" void kernel_launch(void* const* d_in, const int* in_sizes, int n_in,
                              void* d_out, int out_size, void* d_ws, size_t ws_size,
                              hipStream_t stream) {
  const float* x  = (const float*)d_in[0];
  const float* Wq = (const float*)d_in[1];
  const float* Wk = (const float*)d_in[2];
  const float* Wv = (const float*)d_in[3];
  const float* Wb = (const float*)d_in[4];
  const float* Wo = (const float*)d_in[5];
  const float* cq = (const float*)d_in[6];
  const float* ck = (const float*)d_in[7];
  const float* cv = (const float*)d_in[8];
  const float* rw = (const float*)d_in[9];

  // ---- d_out (64MB) doubles as scratch ----
  // [0:32MB): xb (bf16 x) until GEMM1, then o (bf16 rec output) until rmsn
  // [32:64MB): v (bf16) until rec done. Final GEMM2 overwrites all 64MB with fp32 out.
  unsigned short* xb  = (unsigned short*)d_out;
  unsigned short* vb  = (unsigned short*)d_out + (size_t)ROWS * Hm;
  unsigned short* o_b = (unsigned short*)d_out;
  float* out = (float*)d_out;

  // ---- ws: ~192.5 MB total ----
  char* ws = (char*)d_ws;
  size_t off = 0;
  auto alloc = [&](size_t bytes) {
    void* p = ws + off;
    off = (off + bytes + 255) & ~(size_t)255;
    return p;
  };
  unsigned short* wqkv = (unsigned short*)alloc((size_t)QKVN * Hm * 2);  // 24MB
  unsigned short* wob  = (unsigned short*)alloc((size_t)Hm * Hm * 2);    //  8MB
  unsigned short* qkvh = (unsigned short*)alloc((size_t)ROWS * QKVN * 2);// 96MB
  unsigned short* qb   = (unsigned short*)alloc((size_t)ROWS * Hm * 2);  // 32MB
  unsigned short* kb   = (unsigned short*)alloc((size_t)ROWS * Hm * 2);  // 32MB
  float* beta          = (float*)alloc((size_t)ROWS * NHh * 4);          // 0.5MB
  unsigned short* obb  = qkvh;  // alias: qkvh dead after conv; obb needs 32MB <= 96MB

  cast_x_k<<<ROWS * Hm / 1024, 256, 0, stream>>>(x, xb);
  cast_w_k<<<Hm * Hm / 256, 256, 0, stream>>>(Wq, Wk, Wv, Wo, wqkv, wob);
  gemm_bt<true><<<dim3(QKVN / 128, ROWS / 128), 256, 0, stream>>>(xb, wqkv, qkvh, ROWS, QKVN, Hm);
  beta_k<<<ROWS / 4, 256, 0, stream>>>(x, Wb, beta);
  conv_k<<<dim3(Hm / 256, Ss / 32, Bb * 3), 256, 0, stream>>>(qkvh, cq, ck, cv, qb, kb, vb);
  rec_k<<<256, 256, 0, stream>>>(qb, kb, vb, beta, o_b);
  rmsn_k<<<ROWS, 256, 0, stream>>>(o_b, rw, obb);
  gemm_bt<false><<<dim3(Hm / 128, ROWS / 128), 256, 0, stream>>>(obb, wob, out, ROWS, Hm, Hm);
}

// Round 3
// 1298.804 us; speedup vs baseline: 2.5528x; 2.5528x over previous
//
#include <hip/hip_runtime.h>

#define DI __device__ __forceinline__

constexpr int Bb = 2, Ss = 4096, Hm = 2048, NHh = 16, HDd = 128;
constexpr int ROWS = Bb * Ss;   // 8192
constexpr int QKVN = 3 * Hm;    // 6144
constexpr int CC = 64;          // chunk length
constexpr int NC = Ss / CC;     // 64 chunks per (b,h)

typedef __bf16 bf16x8 __attribute__((ext_vector_type(8)));
typedef float f32x4 __attribute__((ext_vector_type(4)));

DI unsigned short f2bf(float f) {
  unsigned int u = __float_as_uint(f);
  u = u + 0x7FFFu + ((u >> 16) & 1u);   // round-to-nearest-even
  return (unsigned short)(u >> 16);
}
DI float bf2f(unsigned int u) { return __uint_as_float(u << 16); }
DI void ld_bf8(const unsigned short* p, float* f) {
  uint4 u = *(const uint4*)p;
  f[0] = bf2f(u.x & 0xffffu); f[1] = bf2f(u.x >> 16);
  f[2] = bf2f(u.y & 0xffffu); f[3] = bf2f(u.y >> 16);
  f[4] = bf2f(u.z & 0xffffu); f[5] = bf2f(u.z >> 16);
  f[6] = bf2f(u.w & 0xffffu); f[7] = bf2f(u.w >> 16);
}

// ---------------- cast x -> bf16 ----------------
__global__ void cast_x_k(const float* __restrict__ x, unsigned short* __restrict__ xb) {
  int i = blockIdx.x * 256 + threadIdx.x;
  float4 f = ((const float4*)x)[i];
  ushort4 u;
  u.x = f2bf(f.x); u.y = f2bf(f.y); u.z = f2bf(f.z); u.w = f2bf(f.w);
  ((ushort4*)xb)[i] = u;
}

// ---------------- cast weights -> bf16 (Wq|Wk|Wv concat, Wo) ----------------
__global__ void cast_w_k(const float* __restrict__ Wq, const float* __restrict__ Wk,
                         const float* __restrict__ Wv, const float* __restrict__ Wo,
                         unsigned short* __restrict__ wqkv, unsigned short* __restrict__ wo) {
  const int W1 = Hm * Hm;
  int idx = blockIdx.x * 256 + threadIdx.x;
  for (int r = 0; r < 4; r++) {
    int i = idx + r * W1;
    if (i < W1)            wqkv[i] = f2bf(Wq[i]);
    else if (i < 2 * W1)   wqkv[i] = f2bf(Wk[i - W1]);
    else if (i < 3 * W1)   wqkv[i] = f2bf(Wv[i - 2 * W1]);
    else                   wo[i - 3 * W1] = f2bf(Wo[i - 3 * W1]);
  }
}

// ---------------- bf16 NT GEMM: C[M][N] = A[M][Kd] * B[N][Kd]^T ----------------
template <bool BF16_OUT>
__global__ __launch_bounds__(256) void gemm_bt(const unsigned short* __restrict__ A,
                                               const unsigned short* __restrict__ Bm,
                                               void* __restrict__ Cout,
                                               int M, int N, int Kd) {
  __shared__ __align__(16) unsigned short As[128 * 32];
  __shared__ __align__(16) unsigned short Bs[128 * 32];
  int tid = threadIdx.x;
  int bm = blockIdx.y * 128, bn = blockIdx.x * 128;
  int wave = tid >> 6, lane = tid & 63;
  int wm = (wave >> 1) * 64, wn = (wave & 1) * 64;
  int lm = lane & 15, lq = lane >> 4;
  f32x4 acc[4][4] = {};
  int lr = tid >> 2;
  int lc = (tid & 3) * 8;

  for (int k0 = 0; k0 < Kd; k0 += 32) {
    __syncthreads();
    *(uint4*)&As[lr * 32 + lc]        = *(const uint4*)&A[(size_t)(bm + lr) * Kd + k0 + lc];
    *(uint4*)&As[(lr + 64) * 32 + lc] = *(const uint4*)&A[(size_t)(bm + lr + 64) * Kd + k0 + lc];
    *(uint4*)&Bs[lr * 32 + lc]        = *(const uint4*)&Bm[(size_t)(bn + lr) * Kd + k0 + lc];
    *(uint4*)&Bs[(lr + 64) * 32 + lc] = *(const uint4*)&Bm[(size_t)(bn + lr + 64) * Kd + k0 + lc];
    __syncthreads();
    bf16x8 af[4], bfr[4];
#pragma unroll
    for (int i = 0; i < 4; i++) af[i]  = *(const bf16x8*)&As[(wm + i * 16 + lm) * 32 + lq * 8];
#pragma unroll
    for (int j = 0; j < 4; j++) bfr[j] = *(const bf16x8*)&Bs[(wn + j * 16 + lm) * 32 + lq * 8];
#pragma unroll
    for (int i = 0; i < 4; i++)
#pragma unroll
      for (int j = 0; j < 4; j++)
        acc[i][j] = __builtin_amdgcn_mfma_f32_16x16x32_bf16(af[i], bfr[j], acc[i][j], 0, 0, 0);
  }
#pragma unroll
  for (int i = 0; i < 4; i++)
#pragma unroll
    for (int j = 0; j < 4; j++) {
      int row = bm + wm + i * 16 + lq * 4;
      int col = bn + wn + j * 16 + lm;
#pragma unroll
      for (int r = 0; r < 4; r++) {
        if (BF16_OUT)
          ((unsigned short*)Cout)[(size_t)(row + r) * N + col] = f2bf(acc[i][j][r]);
        else
          ((float*)Cout)[(size_t)(row + r) * N + col] = acc[i][j][r];
      }
    }
}

// ---------------- causal conv K=4 + silu + (l2norm for q/k), bf16 in/out ----------------
__global__ __launch_bounds__(256) void conv_k(const unsigned short* __restrict__ qkvh,
                                              const float* __restrict__ cwq,
                                              const float* __restrict__ cwk,
                                              const float* __restrict__ cwv,
                                              unsigned short* __restrict__ qb,
                                              unsigned short* __restrict__ kb,
                                              unsigned short* __restrict__ vb) {
  __shared__ __align__(16) float sm[32 * 256];
  __shared__ float fac[64];
  int tid = threadIdx.x;
  int cblk = blockIdx.x * 256;
  int s0 = blockIdx.y * 32;
  int z = blockIdx.z;
  int sel = z >> 1, b = z & 1;
  const float* cw = sel == 0 ? cwq : (sel == 1 ? cwk : cwv);
  int c = cblk + tid;
  float4 w = ((const float4*)cw)[c];
  const unsigned short* in = qkvh + (size_t)b * Ss * QKVN + sel * Hm + c;
  float x0 = (s0 >= 3) ? bf2f(in[(size_t)(s0 - 3) * QKVN]) : 0.f;
  float x1 = (s0 >= 2) ? bf2f(in[(size_t)(s0 - 2) * QKVN]) : 0.f;
  float x2 = (s0 >= 1) ? bf2f(in[(size_t)(s0 - 1) * QKVN]) : 0.f;
  for (int si = 0; si < 32; si++) {
    float x3 = bf2f(in[(size_t)(s0 + si) * QKVN]);
    float a = w.x * x0 + w.y * x1 + w.z * x2 + w.w * x3;
    sm[si * 256 + tid] = a / (1.f + __expf(-a));
    x0 = x1; x1 = x2; x2 = x3;
  }
  __syncthreads();
  if (sel < 2) {
    int si = tid >> 3, p = tid & 7;
    const float* row = &sm[si * 256 + p * 32];
    float ss = 0.f;
#pragma unroll
    for (int j = 0; j < 32; j += 4) {
      float4 v4 = *(const float4*)(row + j);
      ss += v4.x * v4.x + v4.y * v4.y + v4.z * v4.z + v4.w * v4.w;
    }
    ss += __shfl_xor(ss, 1);
    ss += __shfl_xor(ss, 2);
    float f = rsqrtf(ss + 1e-6f);
    if (sel == 0) f *= 0.08838834764831845f;
    if ((p & 3) == 0) fac[si * 2 + (p >> 2)] = f;
  }
  __syncthreads();
  unsigned short* outp = sel == 0 ? qb : (sel == 1 ? kb : vb);
  int hl = tid >> 7;
  for (int si = 0; si < 32; si++) {
    float val = sm[si * 256 + tid];
    if (sel < 2) val *= fac[si * 2 + hl];
    outp[(size_t)(b * Ss + s0 + si) * Hm + cblk + tid] = f2bf(val);
  }
}

// ---------------- beta = sigmoid(x @ Wb^T), fp32 ----------------
__global__ __launch_bounds__(256) void beta_k(const float* __restrict__ x,
                                              const float* __restrict__ Wbm,
                                              float* __restrict__ beta) {
  int wid = threadIdx.x >> 6, lane = threadIdx.x & 63;
  int row = blockIdx.x * 4 + wid;
  int h = lane & 15, part = lane >> 4;
  const float* xr = x + (size_t)row * Hm + part * 512;
  const float* wr = Wbm + (size_t)h * Hm + part * 512;
  float acc = 0.f;
  for (int j = 0; j < 512; j += 4) {
    float4 xv = *(const float4*)(xr + j);
    float4 wv = *(const float4*)(wr + j);
    acc += xv.x * wv.x + xv.y * wv.y + xv.z * wv.z + xv.w * wv.w;
  }
  acc += __shfl_xor(acc, 16);
  acc += __shfl_xor(acc, 32);
  if (part == 0) beta[(size_t)row * NHh + h] = 1.f / (1.f + __expf(-acc));
}

// ---------------- recA: per-chunk WY precompute ----------------
// grid (NC, 32): chunk c, bh. Outputs: W[cid][t][d], U[cid][t][v], Kt[cid][d][s] (bf16)
__global__ __launch_bounds__(256) void recA_k(const unsigned short* __restrict__ kg,
                                              const unsigned short* __restrict__ vg,
                                              const float* __restrict__ beta,
                                              unsigned short* __restrict__ Wo_,
                                              unsigned short* __restrict__ Uo,
                                              unsigned short* __restrict__ Kto) {
  __shared__ __align__(16) unsigned short Kc[64 * 136];
  __shared__ __align__(16) unsigned short Vt[128 * 72];
  __shared__ __align__(16) unsigned short Kt[128 * 72];
  __shared__ __align__(16) float Afp[64 * 65];
  __shared__ __align__(16) unsigned short Tb[64 * 72];
  __shared__ float bl[64];
  __shared__ float rowbuf[64];
  int tid = threadIdx.x;
  int c = blockIdx.x, bh = blockIdx.y;
  int b = bh >> 4, h = bh & 15;
  size_t cid = (size_t)bh * NC + c;
  size_t rowbase = (size_t)b * Ss + c * CC;
  int wave = tid >> 6, lane = tid & 63, lm = lane & 15, lq = lane >> 4;

  // stage K chunk (coalesced 16B), V chunk transposed (scalar), beta
  for (int idx = tid; idx < 1024; idx += 256) {
    int r = idx >> 4, c8 = (idx & 15) * 8;
    *(uint4*)&Kc[r * 136 + c8] = *(const uint4*)&kg[(rowbase + r) * Hm + h * HDd + c8];
  }
  for (int idx = tid; idx < 8192; idx += 256) {
    int s = idx >> 7, vv = idx & 127;
    Vt[vv * 72 + s] = vg[(rowbase + s) * Hm + h * HDd + vv];
  }
  if (tid < 64) bl[tid] = beta[(rowbase + tid) * NHh + h];
  __syncthreads();

  // Kt = K^T (LDS transpose)
  for (int idx = tid; idx < 8192; idx += 256) {
    int s = idx >> 7, d = idx & 127;
    Kt[d * 72 + s] = Kc[s * 136 + d];
  }
  // A = strict_tril(diag(beta) K K^T): NT(Kc,Kc), mask+scale on write
  {
    f32x4 accA[4] = {};
#pragma unroll
    for (int kk = 0; kk < 4; kk++) {
      bf16x8 af = *(const bf16x8*)&Kc[(wave * 16 + lm) * 136 + kk * 32 + lq * 8];
#pragma unroll
      for (int st = 0; st < 4; st++) {
        bf16x8 bfr = *(const bf16x8*)&Kc[(st * 16 + lm) * 136 + kk * 32 + lq * 8];
        accA[st] = __builtin_amdgcn_mfma_f32_16x16x32_bf16(af, bfr, accA[st], 0, 0, 0);
      }
    }
#pragma unroll
    for (int st = 0; st < 4; st++)
#pragma unroll
      for (int r = 0; r < 4; r++) {
        int t = wave * 16 + lq * 4 + r, s = st * 16 + lm;
        Afp[t * 65 + s] = (t > s) ? accA[st][r] * bl[t] : 0.f;
      }
  }
  __syncthreads();

  // forward substitution: T = (I+A)^-1, strict-lower of Afp overwritten row by row
  for (int i = 1; i < 64; i++) {
    if (tid < 64) rowbuf[tid] = Afp[i * 65 + tid];
    __syncthreads();
    int j = tid >> 2, p = tid & 3;
    float sum = 0.f;
    if (j < i) {
      for (int l = j + 1 + p; l < i; l += 4)
        sum += rowbuf[l] * Afp[l * 65 + j];
      sum += __shfl_xor(sum, 1);
      sum += __shfl_xor(sum, 2);
      if (p == 0) Afp[i * 65 + j] = -rowbuf[j] - sum;
    }
    __syncthreads();
  }

  // Tb[t][s] = T'[t][s] = T[t][s] * beta_s (bf16); also store Kt to global
  for (int idx = tid; idx < 4096; idx += 256) {
    int i = idx >> 6, j = idx & 63;
    float val = (j < i) ? Afp[i * 65 + j] : (j == i ? 1.f : 0.f);
    Tb[i * 72 + j] = f2bf(val * bl[j]);
  }
  for (int idx = tid; idx < 1024; idx += 256) {
    int d = idx >> 3, s8 = (idx & 7) * 8;
    *(uint4*)&Kto[cid * 8192 + d * 64 + s8] = *(const uint4*)&Kt[d * 72 + s8];
  }
  __syncthreads();

  // U = NT(Tb, Vt) -> [t][v];  W = NT(Tb, Kt) -> [t][d]
  {
    unsigned short* Up = Uo + cid * 8192;
    f32x4 accU[8] = {};
#pragma unroll
    for (int kk = 0; kk < 2; kk++) {
      bf16x8 af = *(const bf16x8*)&Tb[(wave * 16 + lm) * 72 + kk * 32 + lq * 8];
#pragma unroll
      for (int vt = 0; vt < 8; vt++) {
        bf16x8 bfr = *(const bf16x8*)&Vt[(vt * 16 + lm) * 72 + kk * 32 + lq * 8];
        accU[vt] = __builtin_amdgcn_mfma_f32_16x16x32_bf16(af, bfr, accU[vt], 0, 0, 0);
      }
    }
#pragma unroll
    for (int vt = 0; vt < 8; vt++)
#pragma unroll
      for (int r = 0; r < 4; r++) {
        int t = wave * 16 + lq * 4 + r, vv = vt * 16 + lm;
        Up[t * 128 + vv] = f2bf(accU[vt][r]);
      }
  }
  {
    unsigned short* Wp = Wo_ + cid * 8192;
    f32x4 accW[8] = {};
#pragma unroll
    for (int kk = 0; kk < 2; kk++) {
      bf16x8 af = *(const bf16x8*)&Tb[(wave * 16 + lm) * 72 + kk * 32 + lq * 8];
#pragma unroll
      for (int dt = 0; dt < 8; dt++) {
        bf16x8 bfr = *(const bf16x8*)&Kt[(dt * 16 + lm) * 72 + kk * 32 + lq * 8];
        accW[dt] = __builtin_amdgcn_mfma_f32_16x16x32_bf16(af, bfr, accW[dt], 0, 0, 0);
      }
    }
#pragma unroll
    for (int dt = 0; dt < 8; dt++)
#pragma unroll
      for (int r = 0; r < 4; r++) {
        int t = wave * 16 + lq * 4 + r, d = dt * 16 + lm;
        Wp[t * 128 + d] = f2bf(accW[dt][r]);
      }
  }
}

// ---------------- recB: sequential chunk scan, state S^T[v][d] in LDS ----------------
// grid (2, 32): v-slice (64 cols), bh. 256 threads, 4 waves.
__global__ __launch_bounds__(256) void recB_k(const unsigned short* __restrict__ qg,
                                              const unsigned short* __restrict__ kg,
                                              const unsigned short* __restrict__ Wg,
                                              const unsigned short* __restrict__ Ug,
                                              const unsigned short* __restrict__ Ktg,
                                              unsigned short* __restrict__ og) {
  __shared__ float St32[64 * 128];                       // 32 KB  S^T fp32 master
  __shared__ __align__(16) unsigned short Stb[64 * 136]; // bf16 operand copy
  __shared__ __align__(16) unsigned short Wc[64 * 136];
  __shared__ __align__(16) unsigned short Qc[64 * 136];
  __shared__ __align__(16) unsigned short Kcb[64 * 136];
  __shared__ __align__(16) unsigned short Ktc[128 * 72];
  __shared__ __align__(16) unsigned short Uc[64 * 72];
  __shared__ __align__(16) unsigned short At[64 * 72];
  __shared__ __align__(16) unsigned short Dt[64 * 72];
  int tid = threadIdx.x;
  int vs = blockIdx.x, bh = blockIdx.y;
  int b = bh >> 4, h = bh & 15;
  int v0 = vs * 64;
  int wave = tid >> 6, lane = tid & 63, lm = lane & 15, lq = lane >> 4;

  for (int i = tid; i < 64 * 128; i += 256) St32[i] = 0.f;
  for (int i = tid; i < 64 * 136; i += 256) Stb[i] = 0;
  __syncthreads();

  for (int c = 0; c < NC; c++) {
    size_t cid = (size_t)bh * NC + c;
    size_t rowbase = (size_t)b * Ss + c * CC;
    const unsigned short* Wp  = Wg + cid * 8192;
    const unsigned short* Ktp = Ktg + cid * 8192;
    const unsigned short* Up  = Ug + cid * 8192 + v0;
    // stage chunk operands
    for (int idx = tid; idx < 1024; idx += 256) {
      int r = idx >> 4, c8 = (idx & 15) * 8;
      *(uint4*)&Wc[r * 136 + c8]  = *(const uint4*)&Wp[r * 128 + c8];
      *(uint4*)&Qc[r * 136 + c8]  = *(const uint4*)&qg[(rowbase + r) * Hm + h * HDd + c8];
      *(uint4*)&Kcb[r * 136 + c8] = *(const uint4*)&kg[(rowbase + r) * Hm + h * HDd + c8];
      int r2 = idx >> 3, d8 = (idx & 7) * 8;
      *(uint4*)&Ktc[r2 * 72 + d8] = *(const uint4*)&Ktp[r2 * 64 + d8];
    }
    for (int idx = tid; idx < 512; idx += 256) {
      int r = idx >> 3, c8 = (idx & 7) * 8;
      *(uint4*)&Uc[r * 72 + c8] = *(const uint4*)&Up[r * 128 + c8];
    }
    __syncthreads();

    // phase 2: At = mask(NT(Qc,Kcb)); WS = NT(Wc,Stb); Dt = (Uc - WS)^T
    {
      f32x4 accA[4] = {};
#pragma unroll
      for (int kk = 0; kk < 4; kk++) {
        bf16x8 af = *(const bf16x8*)&Qc[(wave * 16 + lm) * 136 + kk * 32 + lq * 8];
#pragma unroll
        for (int st = 0; st < 4; st++) {
          bf16x8 bfr = *(const bf16x8*)&Kcb[(st * 16 + lm) * 136 + kk * 32 + lq * 8];
          accA[st] = __builtin_amdgcn_mfma_f32_16x16x32_bf16(af, bfr, accA[st], 0, 0, 0);
        }
      }
#pragma unroll
      for (int st = 0; st < 4; st++)
#pragma unroll
        for (int r = 0; r < 4; r++) {
          int t = wave * 16 + lq * 4 + r, s = st * 16 + lm;
          At[t * 72 + s] = (s <= t) ? f2bf(accA[st][r]) : (unsigned short)0;
        }
    }
    {
      f32x4 accD[4] = {};
#pragma unroll
      for (int kk = 0; kk < 4; kk++) {
        bf16x8 af = *(const bf16x8*)&Wc[(wave * 16 + lm) * 136 + kk * 32 + lq * 8];
#pragma unroll
        for (int vt = 0; vt < 4; vt++) {
          bf16x8 bfr = *(const bf16x8*)&Stb[(vt * 16 + lm) * 136 + kk * 32 + lq * 8];
          accD[vt] = __builtin_amdgcn_mfma_f32_16x16x32_bf16(af, bfr, accD[vt], 0, 0, 0);
        }
      }
#pragma unroll
      for (int vt = 0; vt < 4; vt++)
#pragma unroll
        for (int r = 0; r < 4; r++) {
          int t = wave * 16 + lq * 4 + r, vv = vt * 16 + lm;
          float dval = bf2f(Uc[t * 72 + vv]) - accD[vt][r];
          Dt[vv * 72 + t] = f2bf(dval);
        }
    }
    __syncthreads();

    // phase 3: O = NT(Qc,Stb) + NT(At,Dt) -> global
    {
      f32x4 accO[4] = {};
#pragma unroll
      for (int kk = 0; kk < 4; kk++) {
        bf16x8 af = *(const bf16x8*)&Qc[(wave * 16 + lm) * 136 + kk * 32 + lq * 8];
#pragma unroll
        for (int vt = 0; vt < 4; vt++) {
          bf16x8 bfr = *(const bf16x8*)&Stb[(vt * 16 + lm) * 136 + kk * 32 + lq * 8];
          accO[vt] = __builtin_amdgcn_mfma_f32_16x16x32_bf16(af, bfr, accO[vt], 0, 0, 0);
        }
      }
#pragma unroll
      for (int kk = 0; kk < 2; kk++) {
        bf16x8 af = *(const bf16x8*)&At[(wave * 16 + lm) * 72 + kk * 32 + lq * 8];
#pragma unroll
        for (int vt = 0; vt < 4; vt++) {
          bf16x8 bfr = *(const bf16x8*)&Dt[(vt * 16 + lm) * 72 + kk * 32 + lq * 8];
          accO[vt] = __builtin_amdgcn_mfma_f32_16x16x32_bf16(af, bfr, accO[vt], 0, 0, 0);
        }
      }
#pragma unroll
      for (int vt = 0; vt < 4; vt++)
#pragma unroll
        for (int r = 0; r < 4; r++) {
          int t = wave * 16 + lq * 4 + r, vv = vt * 16 + lm;
          og[(rowbase + t) * Hm + h * HDd + v0 + vv] = f2bf(accO[vt][r]);
        }
    }
    __syncthreads();

    // phase 4: S^T += NT(Dt, Ktc); refresh Stb
    {
      f32x4 accP[8] = {};
#pragma unroll
      for (int kk = 0; kk < 2; kk++) {
        bf16x8 af = *(const bf16x8*)&Dt[(wave * 16 + lm) * 72 + kk * 32 + lq * 8];
#pragma unroll
        for (int dt = 0; dt < 8; dt++) {
          bf16x8 bfr = *(const bf16x8*)&Ktc[(dt * 16 + lm) * 72 + kk * 32 + lq * 8];
          accP[dt] = __builtin_amdgcn_mfma_f32_16x16x32_bf16(af, bfr, accP[dt], 0, 0, 0);
        }
      }
#pragma unroll
      for (int dt = 0; dt < 8; dt++)
#pragma unroll
        for (int r = 0; r < 4; r++) {
          int vv = wave * 16 + lq * 4 + r, d = dt * 16 + lm;
          float ns = St32[vv * 128 + d] + accP[dt][r];
          St32[vv * 128 + d] = ns;
          Stb[vv * 136 + d] = f2bf(ns);
        }
    }
    __syncthreads();
  }
}

// ---------------- RMSNorm over head_dim + bf16 in/out ----------------
__global__ __launch_bounds__(256) void rmsn_k(const unsigned short* __restrict__ o,
                                              const float* __restrict__ rw,
                                              unsigned short* __restrict__ ob) {
  int tid = threadIdx.x;
  size_t rowoff = (size_t)blockIdx.x * Hm + tid * 8;
  float f[8];
  ld_bf8(o + rowoff, f);
  float ss = f[0]*f[0] + f[1]*f[1] + f[2]*f[2] + f[3]*f[3] +
             f[4]*f[4] + f[5]*f[5] + f[6]*f[6] + f[7]*f[7];
  ss += __shfl_xor(ss, 1); ss += __shfl_xor(ss, 2); ss += __shfl_xor(ss, 4); ss += __shfl_xor(ss, 8);
  float sc = rsqrtf(ss * (1.f / 128.f) + 1e-5f);
  int d = (tid & 15) * 8;
  float4 wa = *(const float4*)(rw + d);
  float4 wb = *(const float4*)(rw + d + 4);
  ushort4 u0, u1;
  u0.x = f2bf(f[0] * sc * wa.x); u0.y = f2bf(f[1] * sc * wa.y);
  u0.z = f2bf(f[2] * sc * wa.z); u0.w = f2bf(f[3] * sc * wa.w);
  u1.x = f2bf(f[4] * sc * wb.x); u1.y = f2bf(f[5] * sc * wb.y);
  u1.z = f2bf(f[6] * sc * wb.z); u1.w = f2bf(f[7] * sc * wb.w);
  ((ushort4*)ob)[rowoff / 4] = u0;
  ((ushort4*)ob)[rowoff / 4 + 1] = u1;
}

extern "C" void kernel_launch(void* const* d_in, const int* in_sizes, int n_in,
                              void* d_out, int out_size, void* d_ws, size_t ws_size,
                              hipStream_t stream) {
  const float* x  = (const float*)d_in[0];
  const float* Wq = (const float*)d_in[1];
  const float* Wk = (const float*)d_in[2];
  const float* Wv = (const float*)d_in[3];
  const float* Wb = (const float*)d_in[4];
  const float* Wo = (const float*)d_in[5];
  const float* cq = (const float*)d_in[6];
  const float* ck = (const float*)d_in[7];
  const float* cv = (const float*)d_in[8];
  const float* rw = (const float*)d_in[9];

  // d_out (64MB) as scratch: [0:32) xb then o; [32:64) vb. GEMM2 overwrites with fp32 out.
  unsigned short* xb  = (unsigned short*)d_out;
  unsigned short* vb  = (unsigned short*)d_out + (size_t)ROWS * Hm;
  unsigned short* o_b = (unsigned short*)d_out;
  float* out = (float*)d_out;

  // ws: 192.5 MB (same proven footprint as R2)
  char* ws = (char*)d_ws;
  size_t off = 0;
  auto alloc = [&](size_t bytes) {
    void* p = ws + off;
    off = (off + bytes + 255) & ~(size_t)255;
    return p;
  };
  unsigned short* wqkv = (unsigned short*)alloc((size_t)QKVN * Hm * 2);   // 24MB
  unsigned short* wob  = (unsigned short*)alloc((size_t)Hm * Hm * 2);     //  8MB
  unsigned short* qkvh = (unsigned short*)alloc((size_t)ROWS * QKVN * 2); // 96MB
  unsigned short* qb   = (unsigned short*)alloc((size_t)ROWS * Hm * 2);   // 32MB
  unsigned short* kb   = (unsigned short*)alloc((size_t)ROWS * Hm * 2);   // 32MB
  float* beta          = (float*)alloc((size_t)ROWS * NHh * 4);           // 0.5MB
  // After conv, qkvh is dead: alias WY buffers (3 x 32MB = 96MB exact)
  unsigned short* Wch = qkvh;                              // [2048][64][128]
  unsigned short* Uch = qkvh + (size_t)2048 * 8192;        // [2048][64][128]
  unsigned short* Kth = qkvh + (size_t)2 * 2048 * 8192;    // [2048][128][64]
  unsigned short* obb = qkvh;  // rmsn out, after recB (W region dead)

  cast_x_k<<<ROWS * Hm / 1024, 256, 0, stream>>>(x, xb);
  cast_w_k<<<Hm * Hm / 256, 256, 0, stream>>>(Wq, Wk, Wv, Wo, wqkv, wob);
  gemm_bt<true><<<dim3(QKVN / 128, ROWS / 128), 256, 0, stream>>>(xb, wqkv, qkvh, ROWS, QKVN, Hm);
  beta_k<<<ROWS / 4, 256, 0, stream>>>(x, Wb, beta);
  conv_k<<<dim3(Hm / 256, Ss / 32, Bb * 3), 256, 0, stream>>>(qkvh, cq, ck, cv, qb, kb, vb);
  recA_k<<<dim3(NC, 32), 256, 0, stream>>>(kb, vb, beta, Wch, Uch, Kth);
  recB_k<<<dim3(2, 32), 256, 0, stream>>>(qb, kb, Wch, Uch, Kth, o_b);
  rmsn_k<<<ROWS, 256, 0, stream>>>(o_b, rw, obb);
  gemm_bt<false><<<dim3(Hm / 128, ROWS / 128), 256, 0, stream>>>(obb, wob, out, ROWS, Hm, Hm);
}

// Round 4
// 1249.630 us; speedup vs baseline: 2.6533x; 1.0394x over previous
//
#include <hip/hip_runtime.h>

#define DI __device__ __forceinline__

constexpr int Bb = 2, Ss = 4096, Hm = 2048, NHh = 16, HDd = 128;
constexpr int ROWS = Bb * Ss;   // 8192
constexpr int QKVN = 3 * Hm;    // 6144
constexpr int CC = 64;          // chunk length
constexpr int NC = Ss / CC;     // 64 chunks per (b,h)

typedef __bf16 bf16x8 __attribute__((ext_vector_type(8)));
typedef float f32x4 __attribute__((ext_vector_type(4)));

DI unsigned short f2bf(float f) {
  unsigned int u = __float_as_uint(f);
  u = u + 0x7FFFu + ((u >> 16) & 1u);   // round-to-nearest-even
  return (unsigned short)(u >> 16);
}
DI float bf2f(unsigned int u) { return __uint_as_float(u << 16); }
DI void ld_bf8(const unsigned short* p, float* f) {
  uint4 u = *(const uint4*)p;
  f[0] = bf2f(u.x & 0xffffu); f[1] = bf2f(u.x >> 16);
  f[2] = bf2f(u.y & 0xffffu); f[3] = bf2f(u.y >> 16);
  f[4] = bf2f(u.z & 0xffffu); f[5] = bf2f(u.z >> 16);
  f[6] = bf2f(u.w & 0xffffu); f[7] = bf2f(u.w >> 16);
}

// async global->LDS, 16B/lane, lds dest = base + lane*16 (wave-uniform base)
DI void gld16(const unsigned short* g, unsigned short* l) {
  __builtin_amdgcn_global_load_lds(
      (const __attribute__((address_space(1))) unsigned int*)g,
      (__attribute__((address_space(3))) unsigned int*)l, 16, 0, 0);
}

// ---------------- cast x -> bf16 ----------------
__global__ void cast_x_k(const float* __restrict__ x, unsigned short* __restrict__ xb) {
  int i = blockIdx.x * 256 + threadIdx.x;
  float4 f = ((const float4*)x)[i];
  ushort4 u;
  u.x = f2bf(f.x); u.y = f2bf(f.y); u.z = f2bf(f.z); u.w = f2bf(f.w);
  ((ushort4*)xb)[i] = u;
}

// ---------------- cast weights -> bf16 (Wq|Wk|Wv concat, Wo) ----------------
__global__ void cast_w_k(const float* __restrict__ Wq, const float* __restrict__ Wk,
                         const float* __restrict__ Wv, const float* __restrict__ Wo,
                         unsigned short* __restrict__ wqkv, unsigned short* __restrict__ wo) {
  const int W1 = Hm * Hm;
  int idx = blockIdx.x * 256 + threadIdx.x;
  for (int r = 0; r < 4; r++) {
    int i = idx + r * W1;
    if (i < W1)            wqkv[i] = f2bf(Wq[i]);
    else if (i < 2 * W1)   wqkv[i] = f2bf(Wk[i - W1]);
    else if (i < 3 * W1)   wqkv[i] = f2bf(Wv[i - 2 * W1]);
    else                   wo[i - 3 * W1] = f2bf(Wo[i - 3 * W1]);
  }
}

// ---------------- bf16 NT GEMM, m97-style global_load_lds staging ----------------
template <bool BF16_OUT>
__global__ __launch_bounds__(256) void gemm_bt(const unsigned short* __restrict__ A,
                                               const unsigned short* __restrict__ Bm,
                                               void* __restrict__ Cout,
                                               int M, int N, int Kd) {
  __shared__ __align__(16) unsigned short As[128 * 32];
  __shared__ __align__(16) unsigned short Bs[128 * 32];
  int tid = threadIdx.x;
  int bm = blockIdx.y * 128, bn = blockIdx.x * 128;
  int wave = tid >> 6, lane = tid & 63;
  int wm = (wave >> 1) * 64, wn = (wave & 1) * 64;
  int lm = lane & 15, lq = lane >> 4;
  f32x4 acc[4][4] = {};
  int sr = lane >> 2;        // 0..15 row within 16-row group
  int sc = (lane & 3) * 8;   // col in shorts

  for (int k0 = 0; k0 < Kd; k0 += 32) {
    __syncthreads();
#pragma unroll
    for (int i = 0; i < 2; i++) {
      int inst = (wave << 1) + i;          // 0..7, 16 rows each
      int r = inst * 16 + sr;
      gld16(&A[(size_t)(bm + r) * Kd + k0 + sc], &As[inst * 512]);
      gld16(&Bm[(size_t)(bn + r) * Kd + k0 + sc], &Bs[inst * 512]);
    }
    __syncthreads();
    bf16x8 af[4], bfr[4];
#pragma unroll
    for (int i = 0; i < 4; i++) af[i]  = *(const bf16x8*)&As[(wm + i * 16 + lm) * 32 + lq * 8];
#pragma unroll
    for (int j = 0; j < 4; j++) bfr[j] = *(const bf16x8*)&Bs[(wn + j * 16 + lm) * 32 + lq * 8];
#pragma unroll
    for (int i = 0; i < 4; i++)
#pragma unroll
      for (int j = 0; j < 4; j++)
        acc[i][j] = __builtin_amdgcn_mfma_f32_16x16x32_bf16(af[i], bfr[j], acc[i][j], 0, 0, 0);
  }
#pragma unroll
  for (int i = 0; i < 4; i++)
#pragma unroll
    for (int j = 0; j < 4; j++) {
      int row = bm + wm + i * 16 + lq * 4;
      int col = bn + wn + j * 16 + lm;
#pragma unroll
      for (int r = 0; r < 4; r++) {
        if (BF16_OUT)
          ((unsigned short*)Cout)[(size_t)(row + r) * N + col] = f2bf(acc[i][j][r]);
        else
          ((float*)Cout)[(size_t)(row + r) * N + col] = acc[i][j][r];
      }
    }
}

// ---------------- causal conv K=4 + silu + (l2norm for q/k), bf16 in/out ----------------
__global__ __launch_bounds__(256) void conv_k(const unsigned short* __restrict__ qkvh,
                                              const float* __restrict__ cwq,
                                              const float* __restrict__ cwk,
                                              const float* __restrict__ cwv,
                                              unsigned short* __restrict__ qb,
                                              unsigned short* __restrict__ kb,
                                              unsigned short* __restrict__ vb) {
  __shared__ __align__(16) float sm[32 * 260];   // pad 260: bank stride 4, not 0
  __shared__ float fac[64];
  int tid = threadIdx.x;
  int cblk = blockIdx.x * 256;
  int s0 = blockIdx.y * 32;
  int z = blockIdx.z;
  int sel = z >> 1, b = z & 1;
  const float* cw = sel == 0 ? cwq : (sel == 1 ? cwk : cwv);
  int c = cblk + tid;
  float4 w = ((const float4*)cw)[c];
  const unsigned short* in = qkvh + (size_t)b * Ss * QKVN + sel * Hm + c;
  float x0 = (s0 >= 3) ? bf2f(in[(size_t)(s0 - 3) * QKVN]) : 0.f;
  float x1 = (s0 >= 2) ? bf2f(in[(size_t)(s0 - 2) * QKVN]) : 0.f;
  float x2 = (s0 >= 1) ? bf2f(in[(size_t)(s0 - 1) * QKVN]) : 0.f;
  for (int si = 0; si < 32; si++) {
    float x3 = bf2f(in[(size_t)(s0 + si) * QKVN]);
    float a = w.x * x0 + w.y * x1 + w.z * x2 + w.w * x3;
    sm[si * 260 + tid] = a / (1.f + __expf(-a));
    x0 = x1; x1 = x2; x2 = x3;
  }
  __syncthreads();
  if (sel < 2) {
    int si = tid >> 3, p = tid & 7;
    const float* row = &sm[si * 260 + p * 32];
    float ss = 0.f;
#pragma unroll
    for (int j = 0; j < 32; j += 4) {
      float4 v4 = *(const float4*)(row + j);
      ss += v4.x * v4.x + v4.y * v4.y + v4.z * v4.z + v4.w * v4.w;
    }
    ss += __shfl_xor(ss, 1);
    ss += __shfl_xor(ss, 2);
    float f = rsqrtf(ss + 1e-6f);
    if (sel == 0) f *= 0.08838834764831845f;
    if ((p & 3) == 0) fac[si * 2 + (p >> 2)] = f;
  }
  __syncthreads();
  unsigned short* outp = sel == 0 ? qb : (sel == 1 ? kb : vb);
  int hl = tid >> 7;
  for (int si = 0; si < 32; si++) {
    float val = sm[si * 260 + tid];
    if (sel < 2) val *= fac[si * 2 + hl];
    outp[(size_t)(b * Ss + s0 + si) * Hm + cblk + tid] = f2bf(val);
  }
}

// ---------------- beta = sigmoid(x @ Wb^T), fp32 ----------------
__global__ __launch_bounds__(256) void beta_k(const float* __restrict__ x,
                                              const float* __restrict__ Wbm,
                                              float* __restrict__ beta) {
  int wid = threadIdx.x >> 6, lane = threadIdx.x & 63;
  int row = blockIdx.x * 4 + wid;
  int h = lane & 15, part = lane >> 4;
  const float* xr = x + (size_t)row * Hm + part * 512;
  const float* wr = Wbm + (size_t)h * Hm + part * 512;
  float acc = 0.f;
  for (int j = 0; j < 512; j += 4) {
    float4 xv = *(const float4*)(xr + j);
    float4 wv = *(const float4*)(wr + j);
    acc += xv.x * wv.x + xv.y * wv.y + xv.z * wv.z + xv.w * wv.w;
  }
  acc += __shfl_xor(acc, 16);
  acc += __shfl_xor(acc, 32);
  if (part == 0) beta[(size_t)row * NHh + h] = 1.f / (1.f + __expf(-acc));
}

// ---------------- recA: per-chunk WY precompute + At, doubling-based inverse ----------------
// grid (NC, 32). Outputs: W[cid][t][d], U[cid][t][v], Kt[cid][d][s]; At into kg's own chunk cols [0,64)
__global__ __launch_bounds__(256) void recA_k(const unsigned short* __restrict__ qg,
                                              unsigned short* kg,   // read K, write At
                                              const unsigned short* __restrict__ vg,
                                              const float* __restrict__ beta,
                                              unsigned short* __restrict__ Wo_,
                                              unsigned short* __restrict__ Uo,
                                              unsigned short* __restrict__ Kto) {
  __shared__ __align__(16) unsigned short Kc[64 * 136];
  __shared__ __align__(16) unsigned short Qc[64 * 136];
  __shared__ __align__(16) unsigned short Vt[128 * 72];
  __shared__ __align__(16) unsigned short Kt[128 * 72];
  __shared__ __align__(16) unsigned short Xa[64 * 72], Xat[64 * 72];
  __shared__ __align__(16) unsigned short Xb2[64 * 72], Xbt[64 * 72];
  __shared__ __align__(16) unsigned short Pa[64 * 72], Pb[64 * 72];
  __shared__ float bl[64];
  int tid = threadIdx.x;
  int c = blockIdx.x, bh = blockIdx.y;
  int b = bh >> 4, h = bh & 15;
  size_t cid = (size_t)bh * NC + c;
  size_t rowbase = (size_t)b * Ss + (size_t)c * CC;
  int wave = tid >> 6, lane = tid & 63, lm = lane & 15, lq = lane >> 4;

  // stage K, Q chunks (16B), V transposed (scalar), beta
  for (int idx = tid; idx < 1024; idx += 256) {
    int r = idx >> 4, c8 = (idx & 15) * 8;
    *(uint4*)&Kc[r * 136 + c8] = *(const uint4*)&kg[(rowbase + r) * Hm + h * HDd + c8];
    *(uint4*)&Qc[r * 136 + c8] = *(const uint4*)&qg[(rowbase + r) * Hm + h * HDd + c8];
  }
  for (int idx = tid; idx < 8192; idx += 256) {
    int s = idx >> 7, vv = idx & 127;
    Vt[vv * 72 + s] = vg[(rowbase + s) * Hm + h * HDd + vv];
  }
  if (tid < 64) bl[tid] = beta[(rowbase + tid) * NHh + h];
  __syncthreads();

  // Kt = K^T (LDS transpose)
  for (int idx = tid; idx < 8192; idx += 256) {
    int s = idx >> 7, d = idx & 127;
    Kt[d * 72 + s] = Kc[s * 136 + d];
  }
  // accA = K K^T -> M = -strict_tril(diag(beta) K K^T); write M, M^T, P0 = I + M
  {
    f32x4 accA[4] = {};
#pragma unroll
    for (int kk = 0; kk < 4; kk++) {
      bf16x8 af = *(const bf16x8*)&Kc[(wave * 16 + lm) * 136 + kk * 32 + lq * 8];
#pragma unroll
      for (int st = 0; st < 4; st++) {
        bf16x8 bfr = *(const bf16x8*)&Kc[(st * 16 + lm) * 136 + kk * 32 + lq * 8];
        accA[st] = __builtin_amdgcn_mfma_f32_16x16x32_bf16(af, bfr, accA[st], 0, 0, 0);
      }
    }
#pragma unroll
    for (int st = 0; st < 4; st++)
#pragma unroll
      for (int r = 0; r < 4; r++) {
        int t = wave * 16 + lq * 4 + r, s = st * 16 + lm;
        float m = (t > s) ? -bl[t] * accA[st][r] : 0.f;
        unsigned short mb = f2bf(m);
        Xa[t * 72 + s] = mb;
        Xat[s * 72 + t] = mb;
        Pa[t * 72 + s] = (t == s) ? f2bf(1.f) : mb;
      }
  }
  // At = mask(Q K^T) written into kg's own chunk region cols [0,64)
  {
    f32x4 accQ[4] = {};
#pragma unroll
    for (int kk = 0; kk < 4; kk++) {
      bf16x8 af = *(const bf16x8*)&Qc[(wave * 16 + lm) * 136 + kk * 32 + lq * 8];
#pragma unroll
      for (int st = 0; st < 4; st++) {
        bf16x8 bfr = *(const bf16x8*)&Kc[(st * 16 + lm) * 136 + kk * 32 + lq * 8];
        accQ[st] = __builtin_amdgcn_mfma_f32_16x16x32_bf16(af, bfr, accQ[st], 0, 0, 0);
      }
    }
#pragma unroll
    for (int st = 0; st < 4; st++)
#pragma unroll
      for (int r = 0; r < 4; r++) {
        int t = wave * 16 + lq * 4 + r, s = st * 16 + lm;
        kg[(rowbase + t) * Hm + h * HDd + s] = (s <= t) ? f2bf(accQ[st][r]) : (unsigned short)0;
      }
  }
  __syncthreads();

  // doubling: T = (I-M)^-1 = prod_{k=0..5} (I + M^(2^k)); carry (X, X^T) pairs
  unsigned short *X = Xa, *Xt = Xat, *Xn = Xb2, *Xnt = Xbt, *P = Pa, *Pn = Pb;
  for (int lvl = 1; lvl <= 5; lvl++) {
    // Xn = NT(X, Xt) = X*X ; Xnt = NT(Xt, X) = (X*X)^T
    f32x4 a1[4] = {}, a2[4] = {};
#pragma unroll
    for (int kk = 0; kk < 2; kk++) {
      bf16x8 afx  = *(const bf16x8*)&X[(wave * 16 + lm) * 72 + kk * 32 + lq * 8];
      bf16x8 afxt = *(const bf16x8*)&Xt[(wave * 16 + lm) * 72 + kk * 32 + lq * 8];
#pragma unroll
      for (int st = 0; st < 4; st++) {
        bf16x8 bx  = *(const bf16x8*)&X[(st * 16 + lm) * 72 + kk * 32 + lq * 8];
        bf16x8 bxt = *(const bf16x8*)&Xt[(st * 16 + lm) * 72 + kk * 32 + lq * 8];
        a1[st] = __builtin_amdgcn_mfma_f32_16x16x32_bf16(afx, bxt, a1[st], 0, 0, 0);
        a2[st] = __builtin_amdgcn_mfma_f32_16x16x32_bf16(afxt, bx, a2[st], 0, 0, 0);
      }
    }
#pragma unroll
    for (int st = 0; st < 4; st++)
#pragma unroll
      for (int r = 0; r < 4; r++) {
        int t = wave * 16 + lq * 4 + r, s = st * 16 + lm;
        Xn[t * 72 + s]  = f2bf(a1[st][r]);
        Xnt[t * 72 + s] = f2bf(a2[st][r]);
      }
    __syncthreads();
    // Pn = P + P*Xn = NT(P, Xnt) with acc seeded by P
    f32x4 ap[4];
#pragma unroll
    for (int st = 0; st < 4; st++)
#pragma unroll
      for (int r = 0; r < 4; r++)
        ap[st][r] = bf2f(P[(wave * 16 + lq * 4 + r) * 72 + st * 16 + lm]);
#pragma unroll
    for (int kk = 0; kk < 2; kk++) {
      bf16x8 afp = *(const bf16x8*)&P[(wave * 16 + lm) * 72 + kk * 32 + lq * 8];
#pragma unroll
      for (int st = 0; st < 4; st++) {
        bf16x8 bxnt = *(const bf16x8*)&Xnt[(st * 16 + lm) * 72 + kk * 32 + lq * 8];
        ap[st] = __builtin_amdgcn_mfma_f32_16x16x32_bf16(afp, bxnt, ap[st], 0, 0, 0);
      }
    }
#pragma unroll
    for (int st = 0; st < 4; st++)
#pragma unroll
      for (int r = 0; r < 4; r++) {
        int t = wave * 16 + lq * 4 + r, s = st * 16 + lm;
        // last level: fold in diag(beta) -> Tb
        Pn[t * 72 + s] = f2bf((lvl == 5) ? ap[st][r] * bl[s] : ap[st][r]);
      }
    // swap
    unsigned short* tmp;
    tmp = X; X = Xn; Xn = tmp;
    tmp = Xt; Xt = Xnt; Xnt = tmp;
    tmp = P; P = Pn; Pn = tmp;
    __syncthreads();
  }

  // store Kt to global
  for (int idx = tid; idx < 1024; idx += 256) {
    int d = idx >> 3, s8 = (idx & 7) * 8;
    *(uint4*)&Kto[cid * 8192 + d * 64 + s8] = *(const uint4*)&Kt[d * 72 + s8];
  }
  // U = NT(Tb, Vt) ; W = NT(Tb, Kt)   (Tb = P)
  {
    unsigned short* Up = Uo + cid * 8192;
    unsigned short* Wp = Wo_ + cid * 8192;
    f32x4 accU[8] = {}, accW[8] = {};
#pragma unroll
    for (int kk = 0; kk < 2; kk++) {
      bf16x8 af = *(const bf16x8*)&P[(wave * 16 + lm) * 72 + kk * 32 + lq * 8];
#pragma unroll
      for (int nt = 0; nt < 8; nt++) {
        bf16x8 bv = *(const bf16x8*)&Vt[(nt * 16 + lm) * 72 + kk * 32 + lq * 8];
        bf16x8 bk = *(const bf16x8*)&Kt[(nt * 16 + lm) * 72 + kk * 32 + lq * 8];
        accU[nt] = __builtin_amdgcn_mfma_f32_16x16x32_bf16(af, bv, accU[nt], 0, 0, 0);
        accW[nt] = __builtin_amdgcn_mfma_f32_16x16x32_bf16(af, bk, accW[nt], 0, 0, 0);
      }
    }
#pragma unroll
    for (int nt = 0; nt < 8; nt++)
#pragma unroll
      for (int r = 0; r < 4; r++) {
        int t = wave * 16 + lq * 4 + r, n = nt * 16 + lm;
        Up[t * 128 + n] = f2bf(accU[nt][r]);
        Wp[t * 128 + n] = f2bf(accW[nt][r]);
      }
  }
}

// ---------------- recB: sequential chunk scan, 256 WGs (8 v-slices x 32 bh) ----------------
__global__ __launch_bounds__(256) void recB_k(const unsigned short* __restrict__ qg,
                                              const unsigned short* __restrict__ atg,
                                              const unsigned short* __restrict__ Wg,
                                              const unsigned short* __restrict__ Ug,
                                              const unsigned short* __restrict__ Ktg,
                                              unsigned short* __restrict__ og) {
  __shared__ __align__(16) unsigned short Wc[64 * 136];
  __shared__ __align__(16) unsigned short Qc[64 * 136];
  __shared__ __align__(16) unsigned short Ktc[128 * 72];
  __shared__ __align__(16) unsigned short Atc[64 * 72];
  __shared__ __align__(16) unsigned short Uc[64 * 24];
  __shared__ __align__(16) unsigned short Dt[16 * 72];
  __shared__ __align__(16) unsigned short Stb[16 * 136];
  __shared__ float St32[16 * 132];
  int tid = threadIdx.x;
  int vs = blockIdx.x, bh = blockIdx.y;
  int b = bh >> 4, h = bh & 15, v0 = vs * 16;
  int wave = tid >> 6, lane = tid & 63, lm = lane & 15, lq = lane >> 4;

  for (int i = tid; i < 16 * 132; i += 256) St32[i] = 0.f;
  for (int i = tid; i < 16 * 136; i += 256) Stb[i] = 0;

  // prologue: stage chunk 0 directly
  {
    size_t cid0 = (size_t)bh * NC;
    size_t rb0 = (size_t)b * Ss;
    const unsigned short* Wp = Wg + cid0 * 8192;
    const unsigned short* Ktp = Ktg + cid0 * 8192;
    const unsigned short* Up = Ug + cid0 * 8192 + v0;
#pragma unroll
    for (int j = 0; j < 4; j++) {
      int idx = tid + j * 256;
      int r = idx >> 4, c8 = (idx & 15) * 8;
      *(uint4*)&Wc[r * 136 + c8] = *(const uint4*)&Wp[r * 128 + c8];
      *(uint4*)&Qc[r * 136 + c8] = *(const uint4*)&qg[(rb0 + r) * Hm + h * HDd + c8];
      int r2 = idx >> 3, d8 = (idx & 7) * 8;
      *(uint4*)&Ktc[r2 * 72 + d8] = *(const uint4*)&Ktp[r2 * 64 + d8];
    }
#pragma unroll
    for (int j = 0; j < 2; j++) {
      int idx = tid + j * 256;
      int t = idx >> 3, s8 = (idx & 7) * 8;
      *(uint4*)&Atc[t * 72 + s8] = *(const uint4*)&atg[(rb0 + t) * Hm + h * HDd + s8];
    }
    if (tid < 128) {
      int t = tid >> 1, c8 = (tid & 1) * 8;
      *(uint4*)&Uc[t * 24 + c8] = *(const uint4*)&Up[t * 128 + c8];
    }
  }
  __syncthreads();

  for (int c = 0; c < NC; c++) {
    size_t rb = (size_t)b * Ss + (size_t)c * CC;
    // issue prefetch of chunk c+1 into registers (consumed in write-slot)
    int cn = (c + 1 < NC) ? c + 1 : c;
    size_t cidn = (size_t)bh * NC + cn;
    size_t rbn = (size_t)b * Ss + (size_t)cn * CC;
    const unsigned short* Wpn = Wg + cidn * 8192;
    const unsigned short* Ktpn = Ktg + cidn * 8192;
    const unsigned short* Upn = Ug + cidn * 8192 + v0;
    uint4 pw[4], pq[4], pk[4], pa[2], pu;
#pragma unroll
    for (int j = 0; j < 4; j++) {
      int idx = tid + j * 256;
      int r = idx >> 4, c8 = (idx & 15) * 8;
      pw[j] = *(const uint4*)&Wpn[r * 128 + c8];
      pq[j] = *(const uint4*)&qg[(rbn + r) * Hm + h * HDd + c8];
      int r2 = idx >> 3, d8 = (idx & 7) * 8;
      pk[j] = *(const uint4*)&Ktpn[r2 * 64 + d8];
    }
#pragma unroll
    for (int j = 0; j < 2; j++) {
      int idx = tid + j * 256;
      int t = idx >> 3, s8 = (idx & 7) * 8;
      pa[j] = *(const uint4*)&atg[(rbn + t) * Hm + h * HDd + s8];
    }
    if (tid < 128) {
      int t = tid >> 1, c8 = (tid & 1) * 8;
      pu = *(const uint4*)&Upn[t * 128 + c8];
    }

    // phase2: accD = NT(Wc, Stb) [64t x 16v]; Dt[v][t] = U - accD
    {
      f32x4 accD = {};
#pragma unroll
      for (int kk = 0; kk < 4; kk++) {
        bf16x8 af = *(const bf16x8*)&Wc[(wave * 16 + lm) * 136 + kk * 32 + lq * 8];
        bf16x8 bfr = *(const bf16x8*)&Stb[lm * 136 + kk * 32 + lq * 8];
        accD = __builtin_amdgcn_mfma_f32_16x16x32_bf16(af, bfr, accD, 0, 0, 0);
      }
#pragma unroll
      for (int r = 0; r < 4; r++) {
        int t = wave * 16 + lq * 4 + r;
        float dv = bf2f(Uc[t * 24 + lm]) - accD[r];
        Dt[lm * 72 + t] = f2bf(dv);
      }
    }
    __syncthreads();

    // phase3+4 fused: accO = NT(Qc,Stb) + NT(Atc,Dt); accP = NT(Dt,Ktc)
    f32x4 accO = {};
    f32x4 accP[2] = {};
    {
#pragma unroll
      for (int kk = 0; kk < 4; kk++) {
        bf16x8 af = *(const bf16x8*)&Qc[(wave * 16 + lm) * 136 + kk * 32 + lq * 8];
        bf16x8 bfr = *(const bf16x8*)&Stb[lm * 136 + kk * 32 + lq * 8];
        accO = __builtin_amdgcn_mfma_f32_16x16x32_bf16(af, bfr, accO, 0, 0, 0);
      }
#pragma unroll
      for (int kk = 0; kk < 2; kk++) {
        bf16x8 af = *(const bf16x8*)&Atc[(wave * 16 + lm) * 72 + kk * 32 + lq * 8];
        bf16x8 bfr = *(const bf16x8*)&Dt[lm * 72 + kk * 32 + lq * 8];
        accO = __builtin_amdgcn_mfma_f32_16x16x32_bf16(af, bfr, accO, 0, 0, 0);
        bf16x8 afd = *(const bf16x8*)&Dt[lm * 72 + kk * 32 + lq * 8];
#pragma unroll
        for (int j = 0; j < 2; j++) {
          int dt = wave * 2 + j;
          bf16x8 bk = *(const bf16x8*)&Ktc[(dt * 16 + lm) * 72 + kk * 32 + lq * 8];
          accP[j] = __builtin_amdgcn_mfma_f32_16x16x32_bf16(afd, bk, accP[j], 0, 0, 0);
        }
      }
    }
    __syncthreads();

    // write-slot: O -> global, state update, store prefetched chunk
#pragma unroll
    for (int r = 0; r < 4; r++) {
      int t = wave * 16 + lq * 4 + r;
      og[(rb + t) * Hm + h * HDd + v0 + lm] = f2bf(accO[r]);
    }
#pragma unroll
    for (int j = 0; j < 2; j++) {
      int dt = wave * 2 + j;
#pragma unroll
      for (int r = 0; r < 4; r++) {
        int vv = lq * 4 + r, d = dt * 16 + lm;
        float ns = St32[vv * 132 + d] + accP[j][r];
        St32[vv * 132 + d] = ns;
        Stb[vv * 136 + d] = f2bf(ns);
      }
    }
#pragma unroll
    for (int j = 0; j < 4; j++) {
      int idx = tid + j * 256;
      int r = idx >> 4, c8 = (idx & 15) * 8;
      *(uint4*)&Wc[r * 136 + c8] = pw[j];
      *(uint4*)&Qc[r * 136 + c8] = pq[j];
      int r2 = idx >> 3, d8 = (idx & 7) * 8;
      *(uint4*)&Ktc[r2 * 72 + d8] = pk[j];
    }
#pragma unroll
    for (int j = 0; j < 2; j++) {
      int idx = tid + j * 256;
      int t = idx >> 3, s8 = (idx & 7) * 8;
      *(uint4*)&Atc[t * 72 + s8] = pa[j];
    }
    if (tid < 128) {
      int t = tid >> 1, c8 = (tid & 1) * 8;
      *(uint4*)&Uc[t * 24 + c8] = pu;
    }
    __syncthreads();
  }
}

// ---------------- RMSNorm over head_dim + bf16 in/out ----------------
__global__ __launch_bounds__(256) void rmsn_k(const unsigned short* __restrict__ o,
                                              const float* __restrict__ rw,
                                              unsigned short* __restrict__ ob) {
  int tid = threadIdx.x;
  size_t rowoff = (size_t)blockIdx.x * Hm + tid * 8;
  float f[8];
  ld_bf8(o + rowoff, f);
  float ss = f[0]*f[0] + f[1]*f[1] + f[2]*f[2] + f[3]*f[3] +
             f[4]*f[4] + f[5]*f[5] + f[6]*f[6] + f[7]*f[7];
  ss += __shfl_xor(ss, 1); ss += __shfl_xor(ss, 2); ss += __shfl_xor(ss, 4); ss += __shfl_xor(ss, 8);
  float sc = rsqrtf(ss * (1.f / 128.f) + 1e-5f);
  int d = (tid & 15) * 8;
  float4 wa = *(const float4*)(rw + d);
  float4 wb = *(const float4*)(rw + d + 4);
  ushort4 u0, u1;
  u0.x = f2bf(f[0] * sc * wa.x); u0.y = f2bf(f[1] * sc * wa.y);
  u0.z = f2bf(f[2] * sc * wa.z); u0.w = f2bf(f[3] * sc * wa.w);
  u1.x = f2bf(f[4] * sc * wb.x); u1.y = f2bf(f[5] * sc * wb.y);
  u1.z = f2bf(f[6] * sc * wb.z); u1.w = f2bf(f[7] * sc * wb.w);
  ((ushort4*)ob)[rowoff / 4] = u0;
  ((ushort4*)ob)[rowoff / 4 + 1] = u1;
}

extern "C" void kernel_launch(void* const* d_in, const int* in_sizes, int n_in,
                              void* d_out, int out_size, void* d_ws, size_t ws_size,
                              hipStream_t stream) {
  const float* x  = (const float*)d_in[0];
  const float* Wq = (const float*)d_in[1];
  const float* Wk = (const float*)d_in[2];
  const float* Wv = (const float*)d_in[3];
  const float* Wb = (const float*)d_in[4];
  const float* Wo = (const float*)d_in[5];
  const float* cq = (const float*)d_in[6];
  const float* ck = (const float*)d_in[7];
  const float* cv = (const float*)d_in[8];
  const float* rw = (const float*)d_in[9];

  // d_out (64MB) as scratch: [0:32) xb then o; [32:64) vb. GEMM2 overwrites with fp32 out.
  unsigned short* xb  = (unsigned short*)d_out;
  unsigned short* vb  = (unsigned short*)d_out + (size_t)ROWS * Hm;
  unsigned short* o_b = (unsigned short*)d_out;
  float* out = (float*)d_out;

  // ws: 192.5 MB (proven footprint)
  char* ws = (char*)d_ws;
  size_t off = 0;
  auto alloc = [&](size_t bytes) {
    void* p = ws + off;
    off = (off + bytes + 255) & ~(size_t)255;
    return p;
  };
  unsigned short* wqkv = (unsigned short*)alloc((size_t)QKVN * Hm * 2);   // 24MB
  unsigned short* wob  = (unsigned short*)alloc((size_t)Hm * Hm * 2);     //  8MB
  unsigned short* qkvh = (unsigned short*)alloc((size_t)ROWS * QKVN * 2); // 96MB
  unsigned short* qb   = (unsigned short*)alloc((size_t)ROWS * Hm * 2);   // 32MB
  unsigned short* kb   = (unsigned short*)alloc((size_t)ROWS * Hm * 2);   // 32MB (K, then At in cols [0,64) per chunk)
  float* beta          = (float*)alloc((size_t)ROWS * NHh * 4);           // 0.5MB
  // After conv, qkvh dead: WY buffers alias it (3 x 32MB = 96MB exact)
  unsigned short* Wch = qkvh;                              // [2048][64][128]
  unsigned short* Uch = qkvh + (size_t)2048 * 8192;        // [2048][64][128]
  unsigned short* Kth = qkvh + (size_t)2 * 2048 * 8192;    // [2048][128][64]
  unsigned short* obb = qkvh;  // rmsn out, after recB (W region dead)

  cast_x_k<<<ROWS * Hm / 1024, 256, 0, stream>>>(x, xb);
  cast_w_k<<<Hm * Hm / 256, 256, 0, stream>>>(Wq, Wk, Wv, Wo, wqkv, wob);
  gemm_bt<true><<<dim3(QKVN / 128, ROWS / 128), 256, 0, stream>>>(xb, wqkv, qkvh, ROWS, QKVN, Hm);
  beta_k<<<ROWS / 4, 256, 0, stream>>>(x, Wb, beta);
  conv_k<<<dim3(Hm / 256, Ss / 32, Bb * 3), 256, 0, stream>>>(qkvh, cq, ck, cv, qb, kb, vb);
  recA_k<<<dim3(NC, 32), 256, 0, stream>>>(qb, kb, vb, beta, Wch, Uch, Kth);
  recB_k<<<dim3(8, 32), 256, 0, stream>>>(qb, kb, Wch, Uch, Kth, o_b);
  rmsn_k<<<ROWS, 256, 0, stream>>>(o_b, rw, obb);
  gemm_bt<false><<<dim3(Hm / 128, ROWS / 128), 256, 0, stream>>>(obb, wob, out, ROWS, Hm, Hm);
}